// Round 2
// baseline (335.547 us; speedup 1.0000x reference)
//
#include <hip/hip_runtime.h>
#include <hip/hip_bf16.h>

typedef float f32x4 __attribute__((ext_vector_type(4)));
typedef unsigned int u32x4 __attribute__((ext_vector_type(4)));
typedef __bf16 bf16x8 __attribute__((ext_vector_type(8)));

#define NSP 4096
#define KTOT 2304

static __device__ __forceinline__ float bflo(unsigned u) {
  return __builtin_bit_cast(float, u << 16);
}
static __device__ __forceinline__ float bfhi(unsigned u) {
  return __builtin_bit_cast(float, u & 0xffff0000u);
}
static __device__ __forceinline__ unsigned short bfbits(float f) {
  return __builtin_bit_cast(unsigned short, (__bf16)f);
}
static __device__ __forceinline__ unsigned packbf2(float f0, float f1) {
  return (unsigned)bfbits(f0) | ((unsigned)bfbits(f1) << 16);
}

// ---------------- x (B,C,H,W) f32 -> XH (B,H,W,C) bf16 ----------------
__global__ __launch_bounds__(256) void k_nhwc(const float* __restrict__ x,
                                              unsigned short* __restrict__ XH) {
  const int by = blockIdx.x;            // b*64 + y
  const int t = threadIdx.x;
  const int xw = t & 63;
  const int cq = t >> 6;                // 0..3
  const float* xp = x + (((by >> 6) * 256 * 64 + (by & 63)) * 64 + xw);
  unsigned short* op = XH + (by * 64 + xw) * 256;
#pragma unroll
  for (int j8 = 0; j8 < 8; ++j8) {
    const int c0 = cq * 64 + j8 * 8;
    u32x4 v;
#pragma unroll
    for (int d = 0; d < 4; ++d) {
      float f0 = xp[(c0 + 2 * d) * 4096];
      float f1 = xp[(c0 + 2 * d + 1) * 4096];
      v[d] = packbf2(f0, f1);
    }
    *(u32x4*)(op + c0) = v;
  }
}

// ---------------- w_conv (Co,C,3,3) f32 -> AW (Co, k*256+c) bf16 ----------------
__global__ void k_wprep(const float* __restrict__ wc, unsigned short* __restrict__ AW) {
  int idx = blockIdx.x * 256 + threadIdx.x;
  if (idx >= 256 * KTOT) return;
  int o = idx / KTOT;
  int r = idx - o * KTOT;
  int k = r >> 8, c = r & 255;
  AW[idx] = bfbits(wc[(o * 256 + c) * 9 + k]);
}

// ---------------- offset conv (fp32, c-split 4, atomic reduce) ----------------
__global__ __launch_bounds__(256) void k_offc(const float* __restrict__ x,
                                              const float* __restrict__ wof,
                                              float* __restrict__ PY,
                                              float* __restrict__ PX,
                                              float* __restrict__ MS) {
  __shared__ float patch[8][18][19];
  const int tid = threadIdx.x;
  const int bx = blockIdx.x;
  const int cs = bx & 3;
  const int tile = (bx >> 2) & 15;
  const int b = bx >> 6;
  const int ty0 = (tile >> 2) * 16, tx0 = (tile & 3) * 16;
  const int tx = tid & 15, ty = tid >> 4;
  float acc[27];
#pragma unroll
  for (int m = 0; m < 27; ++m) acc[m] = 0.f;
  for (int cc = 0; cc < 8; ++cc) {
    const int c0 = cs * 64 + cc * 8;
    __syncthreads();
    for (int idx = tid; idx < 2592; idx += 256) {
      int c = idx / 324;
      int rem = idx - c * 324;
      int rr = rem / 18;
      int col = rem - rr * 18;
      int gy = ty0 - 1 + rr, gx = tx0 - 1 + col;
      float v = 0.f;
      if ((unsigned)gy < 64u && (unsigned)gx < 64u)
        v = x[((b * 256 + c0 + c) * 64 + gy) * 64 + gx];
      patch[c][rr][col] = v;
    }
    __syncthreads();
#pragma unroll 1
    for (int c = 0; c < 8; ++c) {
#pragma unroll
      for (int kh = 0; kh < 3; ++kh) {
#pragma unroll
        for (int kw = 0; kw < 3; ++kw) {
          float xv = patch[c][ty + kh][tx + kw];
          const float* wp = wof + ((c0 + c) * 3 + kh) * 3 + kw;  // + m*2304
#pragma unroll
          for (int m = 0; m < 27; ++m)
            acc[m] = fmaf(xv, wp[m * KTOT], acc[m]);
        }
      }
    }
  }
  const int sp = (ty0 + ty) * 64 + tx0 + tx;
#pragma unroll
  for (int m = 0; m < 9; ++m)
    atomicAdd(&PY[((b * 9 + m) << 12) + sp], acc[m]);
#pragma unroll
  for (int m = 0; m < 9; ++m)
    atomicAdd(&PX[((b * 9 + m) << 12) + sp], acc[9 + m]);
#pragma unroll
  for (int m = 0; m < 9; ++m)
    atomicAdd(&MS[((b * 9 + m) << 12) + sp], acc[18 + m]);
}

// ---------------- in-place: add base grid, sigmoid mask ----------------
__global__ void k_xform2(float* __restrict__ PY, float* __restrict__ PX,
                         float* __restrict__ MS) {
  int idx = blockIdx.x * 256 + threadIdx.x;   // (b*9+k)*4096 + s
  if (idx >= 8 * 9 * NSP) return;
  int s = idx & 4095;
  int k = (idx >> 12) % 9;
  PY[idx] += (float)(s >> 6) - 1.f + (float)(k / 3);
  PX[idx] += (float)(s & 63) - 1.f + (float)(k % 3);
  MS[idx] = 1.f / (1.f + __expf(-MS[idx]));
}

// ---------------- fused sampling + implicit GEMM (bf16 MFMA) ----------------
struct Bld {
  u32x4 g00a, g00b, g01a, g01b, g10a, g10b, g11a, g11b;
  float w00, w01, w10, w11;
};

static __device__ __forceinline__ void loadB(const unsigned short* __restrict__ xb,
                                             const float* __restrict__ PY,
                                             const float* __restrict__ PX,
                                             const float* __restrict__ MS,
                                             int b, int k, int c0, int bc, int s, Bld& r) {
  int ci = (b * 9 + k) * NSP + s;
  float py = PY[ci], px = PX[ci], mk = MS[ci];
  float y0f = floorf(py), x0f = floorf(px);
  float ly = py - y0f, lx = px - x0f;
  int y0 = (int)y0f, x0 = (int)x0f;
  int y1 = y0 + 1, x1 = x0 + 1;
  float omy = 1.f - ly, omx = 1.f - lx;
  float w00 = omy * omx * mk, w01 = omy * lx * mk;
  float w10 = ly * omx * mk, w11 = ly * lx * mk;
  bool y0v = (unsigned)y0 < 64u, y1v = (unsigned)y1 < 64u;
  bool x0v = (unsigned)x0 < 64u, x1v = (unsigned)x1 < 64u;
  r.w00 = (y0v && x0v) ? w00 : 0.f;
  r.w01 = (y0v && x1v) ? w01 : 0.f;
  r.w10 = (y1v && x0v) ? w10 : 0.f;
  r.w11 = (y1v && x1v) ? w11 : 0.f;
  int y0c = min(max(y0, 0), 63), y1c = min(max(y1, 0), 63);
  int x0c = min(max(x0, 0), 63), x1c = min(max(x1, 0), 63);
  int co = c0 + bc;
  const unsigned short* p00 = xb + (y0c * 64 + x0c) * 256 + co;
  const unsigned short* p01 = xb + (y0c * 64 + x1c) * 256 + co;
  const unsigned short* p10 = xb + (y1c * 64 + x0c) * 256 + co;
  const unsigned short* p11 = xb + (y1c * 64 + x1c) * 256 + co;
  r.g00a = *(const u32x4*)p00;
  r.g00b = *(const u32x4*)(p00 + 8);
  r.g01a = *(const u32x4*)p01;
  r.g01b = *(const u32x4*)(p01 + 8);
  r.g10a = *(const u32x4*)p10;
  r.g10b = *(const u32x4*)(p10 + 8);
  r.g11a = *(const u32x4*)p11;
  r.g11b = *(const u32x4*)(p11 + 8);
}

static __device__ __forceinline__ void blendB(const Bld& r, u32x4& o0, u32x4& o1) {
#pragma unroll
  for (int d = 0; d < 4; ++d) {
    float a0 = r.w00 * bflo(r.g00a[d]) + r.w01 * bflo(r.g01a[d]) +
               r.w10 * bflo(r.g10a[d]) + r.w11 * bflo(r.g11a[d]);
    float a1 = r.w00 * bfhi(r.g00a[d]) + r.w01 * bfhi(r.g01a[d]) +
               r.w10 * bfhi(r.g10a[d]) + r.w11 * bfhi(r.g11a[d]);
    o0[d] = packbf2(a0, a1);
    float b0 = r.w00 * bflo(r.g00b[d]) + r.w01 * bflo(r.g01b[d]) +
               r.w10 * bflo(r.g10b[d]) + r.w11 * bflo(r.g11b[d]);
    float b1 = r.w00 * bfhi(r.g00b[d]) + r.w01 * bfhi(r.g01b[d]) +
               r.w10 * bfhi(r.g10b[d]) + r.w11 * bfhi(r.g11b[d]);
    o1[d] = packbf2(b0, b1);
  }
}

__global__ __launch_bounds__(512) void k_gemm(const unsigned short* __restrict__ AW,
                                              const unsigned short* __restrict__ XH,
                                              const float* __restrict__ PY,
                                              const float* __restrict__ PX,
                                              const float* __restrict__ MS,
                                              float* __restrict__ out) {
  __shared__ u32x4 ldsA4[2048];  // 32 KB: A tile [256 rows][64 bf16], 16B-XOR swizzled
  __shared__ u32x4 ldsB4[1024];  // 16 KB: B tile [128 rows][64 bf16]
  unsigned char* ldsA = (unsigned char*)ldsA4;
  unsigned char* ldsB = (unsigned char*)ldsB4;

  const int tid = threadIdx.x;
  const int bid = blockIdx.x;
  const int b = bid >> 5;
  const int s0 = (bid & 31) * 128;

  const int l = tid & 63;
  const int w = tid >> 6;
  const int wm = (w >> 1) * 64;  // 4 M-waves
  const int wn = (w & 1) * 64;   // 2 N-waves

  const int am = tid & 255;
  const int ah = tid >> 8;
  const unsigned short* arow = AW + am * KTOT + ah * 32;
  const unsigned swa = (unsigned)(am & 7) << 4;

  const int bn = tid >> 2;
  const int bc = (tid & 3) * 16;
  const int s = s0 + bn;
  const unsigned swb = (unsigned)(bn & 7) << 4;
  const unsigned short* xb = XH + b * (64 * 64 * 256);

  f32x4 acc[4][4];
#pragma unroll
  for (int i = 0; i < 4; ++i)
#pragma unroll
    for (int j = 0; j < 4; ++j) acc[i][j] = (f32x4){0.f, 0.f, 0.f, 0.f};

  for (int ks = 0; ks < 36; ++ks) {
    const int kn = ks >> 2, cn = (ks & 3) << 6;

    // plain (unpipelined) staging: global loads -> regs
    u32x4 ar[4];
#pragma unroll
    for (int j = 0; j < 4; ++j)
      ar[j] = *(const u32x4*)(arow + kn * 256 + cn + j * 8);
    Bld bld;
    loadB(xb, PY, PX, MS, b, kn, cn, bc, s, bld);
    u32x4 o0, o1;
    blendB(bld, o0, o1);

    __syncthreads();  // previous iteration's MFMA reads done
    {
      const unsigned abase = (unsigned)am * 128u;
#pragma unroll
      for (int j = 0; j < 4; ++j)
        *(u32x4*)(ldsA + abase + (((unsigned)(ah * 64 + j * 16)) ^ swa)) = ar[j];
      const unsigned bbase = (unsigned)bn * 128u;
      *(u32x4*)(ldsB + bbase + (((unsigned)(bc * 2)) ^ swb)) = o0;
      *(u32x4*)(ldsB + bbase + (((unsigned)(bc * 2 + 16)) ^ swb)) = o1;
    }
    __syncthreads();

#pragma unroll
    for (int kk = 0; kk < 2; ++kk) {
      bf16x8 af[4], bfr[4];
      const unsigned co = (unsigned)(kk * 64 + ((l >> 4) * 16));
#pragma unroll
      for (int i = 0; i < 4; ++i) {
        int row = wm + i * 16 + (l & 15);
        af[i] = *(const bf16x8*)(ldsA + (unsigned)row * 128u +
                                 (co ^ ((unsigned)(row & 7) << 4)));
      }
#pragma unroll
      for (int j = 0; j < 4; ++j) {
        int col = wn + j * 16 + (l & 15);
        bfr[j] = *(const bf16x8*)(ldsB + (unsigned)col * 128u +
                                  (co ^ ((unsigned)(col & 7) << 4)));
      }
#pragma unroll
      for (int i = 0; i < 4; ++i)
#pragma unroll
        for (int j = 0; j < 4; ++j)
          acc[i][j] = __builtin_amdgcn_mfma_f32_16x16x32_bf16(af[i], bfr[j],
                                                              acc[i][j], 0, 0, 0);
    }
  }

  // epilogue: D layout col=lane&15, row=(lane>>4)*4+reg (m89)
  const int cn2 = l & 15;
  const int r0 = (l >> 4) * 4;
#pragma unroll
  for (int i = 0; i < 4; ++i) {
#pragma unroll
    for (int j = 0; j < 4; ++j) {
      int sc = s0 + wn + j * 16 + cn2;
#pragma unroll
      for (int r = 0; r < 4; ++r) {
        int o = wm + i * 16 + r0 + r;
        out[((b * 256 + o) << 12) + sc] = acc[i][j][r];
      }
    }
  }
}

extern "C" void kernel_launch(void* const* d_in, const int* in_sizes, int n_in,
                              void* d_out, int out_size, void* d_ws, size_t ws_size,
                              hipStream_t stream) {
  const float* x = (const float*)d_in[0];
  const float* wof = (const float*)d_in[1];
  const float* wc = (const float*)d_in[2];
  float* out = (float*)d_out;
  char* ws = (char*)d_ws;

  // compact workspace: 20.5 MB total
  unsigned short* XH = (unsigned short*)(ws);             // 16,777,216 B
  unsigned short* AW = (unsigned short*)(ws + 16777216);  //  1,179,648 B
  float* PY = (float*)(ws + 17956864);                    //  1,179,648 B
  float* PX = (float*)(ws + 19136512);                    //  1,179,648 B
  float* MS = (float*)(ws + 20316160);                    //  1,179,648 B  (end 21,495,808)

  hipMemsetAsync(ws + 17956864, 0, 3 * 1179648, stream);  // zero PY/PX/MS
  k_nhwc<<<512, 256, 0, stream>>>(x, XH);
  k_wprep<<<2304, 256, 0, stream>>>(wc, AW);
  k_offc<<<512, 256, 0, stream>>>(x, wof, PY, PX, MS);
  k_xform2<<<1152, 256, 0, stream>>>(PY, PX, MS);
  k_gemm<<<256, 512, 0, stream>>>(AW, XH, PY, PX, MS, out);
}

// Round 3
// 238.435 us; speedup vs baseline: 1.4073x; 1.4073x over previous
//
#include <hip/hip_runtime.h>
#include <hip/hip_bf16.h>

typedef float f32x4 __attribute__((ext_vector_type(4)));
typedef unsigned int u32x4 __attribute__((ext_vector_type(4)));
typedef __bf16 bf16x8 __attribute__((ext_vector_type(8)));

#define NSP 4096
#define KTOT 2304

static __device__ __forceinline__ float bflo(unsigned u) {
  return __builtin_bit_cast(float, u << 16);
}
static __device__ __forceinline__ float bfhi(unsigned u) {
  return __builtin_bit_cast(float, u & 0xffff0000u);
}
static __device__ __forceinline__ unsigned short bfbits(float f) {
  return __builtin_bit_cast(unsigned short, (__bf16)f);
}
static __device__ __forceinline__ unsigned packbf2(float f0, float f1) {
  return (unsigned)bfbits(f0) | ((unsigned)bfbits(f1) << 16);
}
static __device__ __forceinline__ float bf16f(unsigned short h) {
  return __builtin_bit_cast(float, (unsigned)h << 16);
}

// ---------- x (B,C,H,W) f32 -> XH (B,H,W,C) bf16 hi + XL bf16 residual ----------
__global__ __launch_bounds__(256) void k_nhwc(const float* __restrict__ x,
                                              unsigned short* __restrict__ XH,
                                              unsigned short* __restrict__ XL) {
  const int by = blockIdx.x;            // b*64 + y
  const int t = threadIdx.x;
  const int xw = t & 63;
  const int cq = t >> 6;                // 0..3
  const float* xp = x + (((by >> 6) * 256 * 64 + (by & 63)) * 64 + xw);
  unsigned short* oh = XH + (by * 64 + xw) * 256;
  unsigned short* ol = XL + (by * 64 + xw) * 256;
#pragma unroll
  for (int j8 = 0; j8 < 8; ++j8) {
    const int c0 = cq * 64 + j8 * 8;
    u32x4 vh, vl;
#pragma unroll
    for (int d = 0; d < 4; ++d) {
      float f0 = xp[(c0 + 2 * d) * 4096];
      float f1 = xp[(c0 + 2 * d + 1) * 4096];
      unsigned short h0 = bfbits(f0), h1 = bfbits(f1);
      float r0 = f0 - bf16f(h0);
      float r1 = f1 - bf16f(h1);
      vh[d] = (unsigned)h0 | ((unsigned)h1 << 16);
      vl[d] = packbf2(r0, r1);
    }
    *(u32x4*)(oh + c0) = vh;
    *(u32x4*)(ol + c0) = vl;
  }
}

// ---------- w_conv (Co,C,3,3) f32 -> AW (Co, k*256+c) bf16 ----------
__global__ void k_wprep(const float* __restrict__ wc, unsigned short* __restrict__ AW) {
  int idx = blockIdx.x * 256 + threadIdx.x;
  if (idx >= 256 * KTOT) return;
  int o = idx / KTOT;
  int r = idx - o * KTOT;
  int k = r >> 8, c = r & 255;
  AW[idx] = bfbits(wc[(o * 256 + c) * 9 + k]);
}

// ---------- w_offset (27,256,3,3) f32 -> AOH/AOL [32][tap*256+c] bf16 hi/lo ----------
__global__ void k_wprep_off(const float* __restrict__ wof,
                            unsigned short* __restrict__ AOH,
                            unsigned short* __restrict__ AOL) {
  int idx = blockIdx.x * 256 + threadIdx.x;   // 32*2304 = 73728
  if (idx >= 32 * KTOT) return;
  int m = idx / KTOT;
  int r = idx - m * KTOT;
  int t = r >> 8, c = r & 255;
  float v = (m < 27) ? wof[(m * 256 + c) * 9 + t] : 0.f;
  unsigned short h = bfbits(v);
  AOH[idx] = h;
  AOL[idx] = bfbits(v - bf16f(h));
}

// ---------- offset conv via split-bf16 MFMA: raw PY/PX/MS logits ----------
__global__ __launch_bounds__(256) void k_offc_mfma(const unsigned short* __restrict__ AOH,
                                                   const unsigned short* __restrict__ AOL,
                                                   const unsigned short* __restrict__ XH,
                                                   const unsigned short* __restrict__ XL,
                                                   float* __restrict__ PY,
                                                   float* __restrict__ PX,
                                                   float* __restrict__ MS) {
  const int tid = threadIdx.x;
  const int l = tid & 63;
  const int w = tid >> 6;                 // 4 waves, each owns 16 cols
  const int bid = blockIdx.x;             // b*64 + y
  const int b = bid >> 6, y = bid & 63;
  const int xcol = w * 16 + (l & 15);
  const int kq = (l >> 4) * 8;            // k sub-offset (elements)
  const unsigned short* xb = XH + b * (64 * 64 * 256);
  const unsigned short* xlb = XL + b * (64 * 64 * 256);
  const int mr = l & 15;

  f32x4 acc0 = (f32x4){0.f, 0.f, 0.f, 0.f};
  f32x4 acc1 = (f32x4){0.f, 0.f, 0.f, 0.f};

#pragma unroll
  for (int tap = 0; tap < 9; ++tap) {
    const int yy = y + tap / 3 - 1;
    const int xx = xcol + tap % 3 - 1;
    const bool valid = ((unsigned)yy < 64u) & ((unsigned)xx < 64u);
    const unsigned short* bp = xb + (yy * 64 + xx) * 256 + kq;
    const unsigned short* blp = xlb + (yy * 64 + xx) * 256 + kq;
    const unsigned short* a0 = AOH + mr * KTOT + tap * 256 + kq;
    const unsigned short* a1 = AOH + (mr + 16) * KTOT + tap * 256 + kq;
    const unsigned short* c0p = AOL + mr * KTOT + tap * 256 + kq;
    const unsigned short* c1p = AOL + (mr + 16) * KTOT + tap * 256 + kq;
#pragma unroll
    for (int kc = 0; kc < 8; ++kc) {
      u32x4 zh = (u32x4){0u, 0u, 0u, 0u};
      u32x4 bhu = valid ? *(const u32x4*)(bp + kc * 32) : zh;
      u32x4 blu = valid ? *(const u32x4*)(blp + kc * 32) : zh;
      bf16x8 bh = __builtin_bit_cast(bf16x8, bhu);
      bf16x8 bl = __builtin_bit_cast(bf16x8, blu);
      bf16x8 ah0 = *(const bf16x8*)(a0 + kc * 32);
      bf16x8 ah1 = *(const bf16x8*)(a1 + kc * 32);
      bf16x8 al0 = *(const bf16x8*)(c0p + kc * 32);
      bf16x8 al1 = *(const bf16x8*)(c1p + kc * 32);
      acc0 = __builtin_amdgcn_mfma_f32_16x16x32_bf16(ah0, bh, acc0, 0, 0, 0);
      acc1 = __builtin_amdgcn_mfma_f32_16x16x32_bf16(ah1, bh, acc1, 0, 0, 0);
      acc0 = __builtin_amdgcn_mfma_f32_16x16x32_bf16(ah0, bl, acc0, 0, 0, 0);
      acc1 = __builtin_amdgcn_mfma_f32_16x16x32_bf16(ah1, bl, acc1, 0, 0, 0);
      acc0 = __builtin_amdgcn_mfma_f32_16x16x32_bf16(al0, bh, acc0, 0, 0, 0);
      acc1 = __builtin_amdgcn_mfma_f32_16x16x32_bf16(al1, bh, acc1, 0, 0, 0);
    }
  }

  // D layout: col=lane&15 (=our n), row=(lane>>4)*4+reg
  const int s = y * 64 + xcol;
#pragma unroll
  for (int mf = 0; mf < 2; ++mf) {
    f32x4 a = mf ? acc1 : acc0;
#pragma unroll
    for (int r = 0; r < 4; ++r) {
      int m = mf * 16 + (l >> 4) * 4 + r;
      if (m < 27) {
        int which = m / 9;
        int mm = m - which * 9;
        float* dst = which == 0 ? PY : (which == 1 ? PX : MS);
        dst[((b * 9 + mm) << 12) + s] = a[r];
      }
    }
  }
}

// ---------- in-place: add base grid, sigmoid mask ----------
__global__ void k_xform2(float* __restrict__ PY, float* __restrict__ PX,
                         float* __restrict__ MS) {
  int idx = blockIdx.x * 256 + threadIdx.x;   // (b*9+k)*4096 + s
  if (idx >= 8 * 9 * NSP) return;
  int s = idx & 4095;
  int k = (idx >> 12) % 9;
  PY[idx] += (float)(s >> 6) - 1.f + (float)(k / 3);
  PX[idx] += (float)(s & 63) - 1.f + (float)(k % 3);
  MS[idx] = 1.f / (1.f + __expf(-MS[idx]));
}

// ---------- fused sampling + implicit GEMM (bf16 MFMA) ----------
struct Bld {
  u32x4 g00a, g00b, g01a, g01b, g10a, g10b, g11a, g11b;
  float w00, w01, w10, w11;
};

static __device__ __forceinline__ void loadB(const unsigned short* __restrict__ xb,
                                             const float* __restrict__ PY,
                                             const float* __restrict__ PX,
                                             const float* __restrict__ MS,
                                             int b, int k, int c0, int bc, int s, Bld& r) {
  int ci = (b * 9 + k) * NSP + s;
  float py = PY[ci], px = PX[ci], mk = MS[ci];
  float y0f = floorf(py), x0f = floorf(px);
  float ly = py - y0f, lx = px - x0f;
  int y0 = (int)y0f, x0 = (int)x0f;
  int y1 = y0 + 1, x1 = x0 + 1;
  float omy = 1.f - ly, omx = 1.f - lx;
  float w00 = omy * omx * mk, w01 = omy * lx * mk;
  float w10 = ly * omx * mk, w11 = ly * lx * mk;
  bool y0v = (unsigned)y0 < 64u, y1v = (unsigned)y1 < 64u;
  bool x0v = (unsigned)x0 < 64u, x1v = (unsigned)x1 < 64u;
  r.w00 = (y0v && x0v) ? w00 : 0.f;
  r.w01 = (y0v && x1v) ? w01 : 0.f;
  r.w10 = (y1v && x0v) ? w10 : 0.f;
  r.w11 = (y1v && x1v) ? w11 : 0.f;
  int y0c = min(max(y0, 0), 63), y1c = min(max(y1, 0), 63);
  int x0c = min(max(x0, 0), 63), x1c = min(max(x1, 0), 63);
  int co = c0 + bc;
  const unsigned short* p00 = xb + (y0c * 64 + x0c) * 256 + co;
  const unsigned short* p01 = xb + (y0c * 64 + x1c) * 256 + co;
  const unsigned short* p10 = xb + (y1c * 64 + x0c) * 256 + co;
  const unsigned short* p11 = xb + (y1c * 64 + x1c) * 256 + co;
  r.g00a = *(const u32x4*)p00;
  r.g00b = *(const u32x4*)(p00 + 8);
  r.g01a = *(const u32x4*)p01;
  r.g01b = *(const u32x4*)(p01 + 8);
  r.g10a = *(const u32x4*)p10;
  r.g10b = *(const u32x4*)(p10 + 8);
  r.g11a = *(const u32x4*)p11;
  r.g11b = *(const u32x4*)(p11 + 8);
}

static __device__ __forceinline__ void blendB(const Bld& r, u32x4& o0, u32x4& o1) {
#pragma unroll
  for (int d = 0; d < 4; ++d) {
    float a0 = r.w00 * bflo(r.g00a[d]) + r.w01 * bflo(r.g01a[d]) +
               r.w10 * bflo(r.g10a[d]) + r.w11 * bflo(r.g11a[d]);
    float a1 = r.w00 * bfhi(r.g00a[d]) + r.w01 * bfhi(r.g01a[d]) +
               r.w10 * bfhi(r.g10a[d]) + r.w11 * bfhi(r.g11a[d]);
    o0[d] = packbf2(a0, a1);
    float b0 = r.w00 * bflo(r.g00b[d]) + r.w01 * bflo(r.g01b[d]) +
               r.w10 * bflo(r.g10b[d]) + r.w11 * bflo(r.g11b[d]);
    float b1 = r.w00 * bfhi(r.g00b[d]) + r.w01 * bfhi(r.g01b[d]) +
               r.w10 * bfhi(r.g10b[d]) + r.w11 * bfhi(r.g11b[d]);
    o1[d] = packbf2(b0, b1);
  }
}

__global__ __launch_bounds__(512) void k_gemm(const unsigned short* __restrict__ AW,
                                              const unsigned short* __restrict__ XH,
                                              const float* __restrict__ PY,
                                              const float* __restrict__ PX,
                                              const float* __restrict__ MS,
                                              float* __restrict__ out) {
  __shared__ u32x4 ldsA4[2048];  // 32 KB: A tile [256 rows][64 bf16], 16B-XOR swizzled
  __shared__ u32x4 ldsB4[1024];  // 16 KB: B tile [128 rows][64 bf16]
  unsigned char* ldsA = (unsigned char*)ldsA4;
  unsigned char* ldsB = (unsigned char*)ldsB4;

  const int tid = threadIdx.x;
  const int bid = blockIdx.x;
  const int b = bid >> 5;
  const int s0 = (bid & 31) * 128;

  const int l = tid & 63;
  const int w = tid >> 6;
  const int wm = (w >> 1) * 64;  // 4 M-waves
  const int wn = (w & 1) * 64;   // 2 N-waves

  const int am = tid & 255;
  const int ah = tid >> 8;
  const unsigned short* arow = AW + am * KTOT + ah * 32;
  const unsigned swa = (unsigned)(am & 7) << 4;

  const int bn = tid >> 2;
  const int bc = (tid & 3) * 16;
  const int s = s0 + bn;
  const unsigned swb = (unsigned)(bn & 7) << 4;
  const unsigned short* xb = XH + b * (64 * 64 * 256);

  f32x4 acc[4][4];
#pragma unroll
  for (int i = 0; i < 4; ++i)
#pragma unroll
    for (int j = 0; j < 4; ++j) acc[i][j] = (f32x4){0.f, 0.f, 0.f, 0.f};

  for (int ks = 0; ks < 36; ++ks) {
    const int kn = ks >> 2, cn = (ks & 3) << 6;

    u32x4 ar[4];
#pragma unroll
    for (int j = 0; j < 4; ++j)
      ar[j] = *(const u32x4*)(arow + kn * 256 + cn + j * 8);
    Bld bld;
    loadB(xb, PY, PX, MS, b, kn, cn, bc, s, bld);
    u32x4 o0, o1;
    blendB(bld, o0, o1);

    __syncthreads();
    {
      const unsigned abase = (unsigned)am * 128u;
#pragma unroll
      for (int j = 0; j < 4; ++j)
        *(u32x4*)(ldsA + abase + (((unsigned)(ah * 64 + j * 16)) ^ swa)) = ar[j];
      const unsigned bbase = (unsigned)bn * 128u;
      *(u32x4*)(ldsB + bbase + (((unsigned)(bc * 2)) ^ swb)) = o0;
      *(u32x4*)(ldsB + bbase + (((unsigned)(bc * 2 + 16)) ^ swb)) = o1;
    }
    __syncthreads();

#pragma unroll
    for (int kk = 0; kk < 2; ++kk) {
      bf16x8 af[4], bfr[4];
      const unsigned co = (unsigned)(kk * 64 + ((l >> 4) * 16));
#pragma unroll
      for (int i = 0; i < 4; ++i) {
        int row = wm + i * 16 + (l & 15);
        af[i] = *(const bf16x8*)(ldsA + (unsigned)row * 128u +
                                 (co ^ ((unsigned)(row & 7) << 4)));
      }
#pragma unroll
      for (int j = 0; j < 4; ++j) {
        int col = wn + j * 16 + (l & 15);
        bfr[j] = *(const bf16x8*)(ldsB + (unsigned)col * 128u +
                                  (co ^ ((unsigned)(col & 7) << 4)));
      }
#pragma unroll
      for (int i = 0; i < 4; ++i)
#pragma unroll
        for (int j = 0; j < 4; ++j)
          acc[i][j] = __builtin_amdgcn_mfma_f32_16x16x32_bf16(af[i], bfr[j],
                                                              acc[i][j], 0, 0, 0);
    }
  }

  const int cn2 = l & 15;
  const int r0 = (l >> 4) * 4;
#pragma unroll
  for (int i = 0; i < 4; ++i) {
#pragma unroll
    for (int j = 0; j < 4; ++j) {
      int sc = s0 + wn + j * 16 + cn2;
#pragma unroll
      for (int r = 0; r < 4; ++r) {
        int o = wm + i * 16 + r0 + r;
        out[((b * 256 + o) << 12) + sc] = acc[i][j][r];
      }
    }
  }
}

extern "C" void kernel_launch(void* const* d_in, const int* in_sizes, int n_in,
                              void* d_out, int out_size, void* d_ws, size_t ws_size,
                              hipStream_t stream) {
  const float* x = (const float*)d_in[0];
  const float* wof = (const float*)d_in[1];
  const float* wc = (const float*)d_in[2];
  float* out = (float*)d_out;
  char* ws = (char*)d_ws;

  // ws layout (total 20.8 MB, safely under the ~32 MiB that round-1 overflowed)
  unsigned short* XH = (unsigned short*)(ws);              // 16,777,216 B
  unsigned short* AW = (unsigned short*)(ws + 16777216);   //  1,179,648 B
  unsigned short* AOH = (unsigned short*)(ws + 17956864);  //    147,456 B
  unsigned short* AOL = (unsigned short*)(ws + 18104320);  //    147,456 B
  float* PY = (float*)(ws + 18251776);                     //  1,179,648 B
  float* PX = (float*)(ws + 19431424);                     //  1,179,648 B
  float* MS = (float*)(ws + 20611072);                     //  1,179,648 B (end 21,790,720)

  // XL (bf16 residual of x, NHWC, 16 MB) lives in d_out: only read by
  // k_offc_mfma, which completes before k_gemm overwrites d_out.
  unsigned short* XL = (unsigned short*)d_out;

  k_nhwc<<<512, 256, 0, stream>>>(x, XH, XL);
  k_wprep<<<2304, 256, 0, stream>>>(wc, AW);
  k_wprep_off<<<288, 256, 0, stream>>>(wof, AOH, AOL);
  k_offc_mfma<<<512, 256, 0, stream>>>(AOH, AOL, XH, XL, PY, PX, MS);
  k_xform2<<<1152, 256, 0, stream>>>(PY, PX, MS);
  k_gemm<<<256, 512, 0, stream>>>(AW, XH, PY, PX, MS, out);
}

// Round 5
// 218.407 us; speedup vs baseline: 1.5363x; 1.0917x over previous
//
#include <hip/hip_runtime.h>
#include <hip/hip_bf16.h>

typedef float f32x4 __attribute__((ext_vector_type(4)));
typedef unsigned int u32x4 __attribute__((ext_vector_type(4)));
typedef __bf16 bf16x8 __attribute__((ext_vector_type(8)));

#define NSP 4096
#define KTOT 2304

static __device__ __forceinline__ float bflo(unsigned u) {
  return __builtin_bit_cast(float, u << 16);
}
static __device__ __forceinline__ float bfhi(unsigned u) {
  return __builtin_bit_cast(float, u & 0xffff0000u);
}
static __device__ __forceinline__ unsigned short bfbits(float f) {
  return __builtin_bit_cast(unsigned short, (__bf16)f);
}
static __device__ __forceinline__ unsigned packbf2(float f0, float f1) {
  return (unsigned)bfbits(f0) | ((unsigned)bfbits(f1) << 16);
}
static __device__ __forceinline__ float bf16f(unsigned short h) {
  return __builtin_bit_cast(float, (unsigned)h << 16);
}

// ---------- x (B,C,H,W) f32 -> XH (B,H,W,C) bf16 hi + XL bf16 residual ----------
__global__ __launch_bounds__(256) void k_nhwc(const float* __restrict__ x,
                                              unsigned short* __restrict__ XH,
                                              unsigned short* __restrict__ XL) {
  const int by = blockIdx.x;            // b*64 + y
  const int t = threadIdx.x;
  const int xw = t & 63;
  const int cq = t >> 6;                // 0..3
  const float* xp = x + (((by >> 6) * 256 * 64 + (by & 63)) * 64 + xw);
  unsigned short* oh = XH + (by * 64 + xw) * 256;
  unsigned short* ol = XL + (by * 64 + xw) * 256;
#pragma unroll
  for (int j8 = 0; j8 < 8; ++j8) {
    const int c0 = cq * 64 + j8 * 8;
    u32x4 vh, vl;
#pragma unroll
    for (int d = 0; d < 4; ++d) {
      float f0 = xp[(c0 + 2 * d) * 4096];
      float f1 = xp[(c0 + 2 * d + 1) * 4096];
      unsigned short h0 = bfbits(f0), h1 = bfbits(f1);
      float r0 = f0 - bf16f(h0);
      float r1 = f1 - bf16f(h1);
      vh[d] = (unsigned)h0 | ((unsigned)h1 << 16);
      vl[d] = packbf2(r0, r1);
    }
    *(u32x4*)(oh + c0) = vh;
    *(u32x4*)(ol + c0) = vl;
  }
}

// ---------- w_conv (Co,C,3,3) f32 -> AW (Co, k*256+c) bf16 ----------
__global__ void k_wprep(const float* __restrict__ wc, unsigned short* __restrict__ AW) {
  int idx = blockIdx.x * 256 + threadIdx.x;
  if (idx >= 256 * KTOT) return;
  int o = idx / KTOT;
  int r = idx - o * KTOT;
  int k = r >> 8, c = r & 255;
  AW[idx] = bfbits(wc[(o * 256 + c) * 9 + k]);
}

// ---------- w_offset (27,256,3,3) f32 -> AOH/AOL [32][tap*256+c] bf16 hi/lo ----------
__global__ void k_wprep_off(const float* __restrict__ wof,
                            unsigned short* __restrict__ AOH,
                            unsigned short* __restrict__ AOL) {
  int idx = blockIdx.x * 256 + threadIdx.x;   // 32*2304 = 73728
  if (idx >= 32 * KTOT) return;
  int m = idx / KTOT;
  int r = idx - m * KTOT;
  int t = r >> 8, c = r & 255;
  float v = (m < 27) ? wof[(m * 256 + c) * 9 + t] : 0.f;
  unsigned short h = bfbits(v);
  AOH[idx] = h;
  AOL[idx] = bfbits(v - bf16f(h));
}

// ---------- offset conv via split-bf16 MFMA: raw PY/PX/MS logits ----------
__global__ __launch_bounds__(256) void k_offc_mfma(const unsigned short* __restrict__ AOH,
                                                   const unsigned short* __restrict__ AOL,
                                                   const unsigned short* __restrict__ XH,
                                                   const unsigned short* __restrict__ XL,
                                                   float* __restrict__ PY,
                                                   float* __restrict__ PX,
                                                   float* __restrict__ MS) {
  const int tid = threadIdx.x;
  const int l = tid & 63;
  const int w = tid >> 6;                 // 4 waves, each owns 16 cols
  const int bid = blockIdx.x;
  const int b = bid & 7;                  // XCD swizzle: one batch per XCD
  const int y = bid >> 3;
  const int xcol = w * 16 + (l & 15);
  const int kq = (l >> 4) * 8;            // k sub-offset (elements)
  const unsigned short* xb = XH + b * (64 * 64 * 256);
  const unsigned short* xlb = XL + b * (64 * 64 * 256);
  const int mr = l & 15;

  f32x4 acc0 = (f32x4){0.f, 0.f, 0.f, 0.f};
  f32x4 acc1 = (f32x4){0.f, 0.f, 0.f, 0.f};

#pragma unroll
  for (int tap = 0; tap < 9; ++tap) {
    const int yy = y + tap / 3 - 1;
    const int xx = xcol + tap % 3 - 1;
    const bool valid = ((unsigned)yy < 64u) & ((unsigned)xx < 64u);
    const unsigned short* bp = xb + (yy * 64 + xx) * 256 + kq;
    const unsigned short* blp = xlb + (yy * 64 + xx) * 256 + kq;
    const unsigned short* a0 = AOH + mr * KTOT + tap * 256 + kq;
    const unsigned short* a1 = AOH + (mr + 16) * KTOT + tap * 256 + kq;
    const unsigned short* c0p = AOL + mr * KTOT + tap * 256 + kq;
    const unsigned short* c1p = AOL + (mr + 16) * KTOT + tap * 256 + kq;
#pragma unroll
    for (int kc = 0; kc < 8; ++kc) {
      u32x4 zh = (u32x4){0u, 0u, 0u, 0u};
      u32x4 bhu = valid ? *(const u32x4*)(bp + kc * 32) : zh;
      u32x4 blu = valid ? *(const u32x4*)(blp + kc * 32) : zh;
      bf16x8 bh = __builtin_bit_cast(bf16x8, bhu);
      bf16x8 bl = __builtin_bit_cast(bf16x8, blu);
      bf16x8 ah0 = *(const bf16x8*)(a0 + kc * 32);
      bf16x8 ah1 = *(const bf16x8*)(a1 + kc * 32);
      bf16x8 al0 = *(const bf16x8*)(c0p + kc * 32);
      bf16x8 al1 = *(const bf16x8*)(c1p + kc * 32);
      acc0 = __builtin_amdgcn_mfma_f32_16x16x32_bf16(ah0, bh, acc0, 0, 0, 0);
      acc1 = __builtin_amdgcn_mfma_f32_16x16x32_bf16(ah1, bh, acc1, 0, 0, 0);
      acc0 = __builtin_amdgcn_mfma_f32_16x16x32_bf16(ah0, bl, acc0, 0, 0, 0);
      acc1 = __builtin_amdgcn_mfma_f32_16x16x32_bf16(ah1, bl, acc1, 0, 0, 0);
      acc0 = __builtin_amdgcn_mfma_f32_16x16x32_bf16(al0, bh, acc0, 0, 0, 0);
      acc1 = __builtin_amdgcn_mfma_f32_16x16x32_bf16(al1, bh, acc1, 0, 0, 0);
    }
  }

  // D layout: col=lane&15 (=our n), row=(lane>>4)*4+reg
  const int s = y * 64 + xcol;
#pragma unroll
  for (int mf = 0; mf < 2; ++mf) {
    f32x4 a = mf ? acc1 : acc0;
#pragma unroll
    for (int r = 0; r < 4; ++r) {
      int m = mf * 16 + (l >> 4) * 4 + r;
      if (m < 27) {
        int which = m / 9;
        int mm = m - which * 9;
        float* dst = which == 0 ? PY : (which == 1 ? PX : MS);
        dst[((b * 9 + mm) << 12) + s] = a[r];
      }
    }
  }
}

// ---------- in-place: add base grid, sigmoid mask ----------
__global__ void k_xform2(float* __restrict__ PY, float* __restrict__ PX,
                         float* __restrict__ MS) {
  int idx = blockIdx.x * 256 + threadIdx.x;   // (b*9+k)*4096 + s
  if (idx >= 8 * 9 * NSP) return;
  int s = idx & 4095;
  int k = (idx >> 12) % 9;
  PY[idx] += (float)(s >> 6) - 1.f + (float)(k / 3);
  PX[idx] += (float)(s & 63) - 1.f + (float)(k % 3);
  MS[idx] = 1.f / (1.f + __expf(-MS[idx]));
}

// ---------- fused sampling + implicit GEMM (bf16 MFMA, double-buffered LDS) ----------
struct Bld {
  u32x4 g00a, g00b, g01a, g01b, g10a, g10b, g11a, g11b;
  float w00, w01, w10, w11;
};

static __device__ __forceinline__ void loadB(const unsigned short* __restrict__ xb,
                                             const float* __restrict__ PY,
                                             const float* __restrict__ PX,
                                             const float* __restrict__ MS,
                                             int b, int k, int c0, int bc, int s, Bld& r) {
  int ci = (b * 9 + k) * NSP + s;
  float py = PY[ci], px = PX[ci], mk = MS[ci];
  float y0f = floorf(py), x0f = floorf(px);
  float ly = py - y0f, lx = px - x0f;
  int y0 = (int)y0f, x0 = (int)x0f;
  int y1 = y0 + 1, x1 = x0 + 1;
  float omy = 1.f - ly, omx = 1.f - lx;
  float w00 = omy * omx * mk, w01 = omy * lx * mk;
  float w10 = ly * omx * mk, w11 = ly * lx * mk;
  bool y0v = (unsigned)y0 < 64u, y1v = (unsigned)y1 < 64u;
  bool x0v = (unsigned)x0 < 64u, x1v = (unsigned)x1 < 64u;
  r.w00 = (y0v && x0v) ? w00 : 0.f;
  r.w01 = (y0v && x1v) ? w01 : 0.f;
  r.w10 = (y1v && x0v) ? w10 : 0.f;
  r.w11 = (y1v && x1v) ? w11 : 0.f;
  int y0c = min(max(y0, 0), 63), y1c = min(max(y1, 0), 63);
  int x0c = min(max(x0, 0), 63), x1c = min(max(x1, 0), 63);
  int co = c0 + bc;
  const unsigned short* p00 = xb + (y0c * 64 + x0c) * 256 + co;
  const unsigned short* p01 = xb + (y0c * 64 + x1c) * 256 + co;
  const unsigned short* p10 = xb + (y1c * 64 + x0c) * 256 + co;
  const unsigned short* p11 = xb + (y1c * 64 + x1c) * 256 + co;
  r.g00a = *(const u32x4*)p00;
  r.g00b = *(const u32x4*)(p00 + 8);
  r.g01a = *(const u32x4*)p01;
  r.g01b = *(const u32x4*)(p01 + 8);
  r.g10a = *(const u32x4*)p10;
  r.g10b = *(const u32x4*)(p10 + 8);
  r.g11a = *(const u32x4*)p11;
  r.g11b = *(const u32x4*)(p11 + 8);
}

static __device__ __forceinline__ void blendB(const Bld& r, u32x4& o0, u32x4& o1) {
#pragma unroll
  for (int d = 0; d < 4; ++d) {
    float a0 = r.w00 * bflo(r.g00a[d]) + r.w01 * bflo(r.g01a[d]) +
               r.w10 * bflo(r.g10a[d]) + r.w11 * bflo(r.g11a[d]);
    float a1 = r.w00 * bfhi(r.g00a[d]) + r.w01 * bfhi(r.g01a[d]) +
               r.w10 * bfhi(r.g10a[d]) + r.w11 * bfhi(r.g11a[d]);
    o0[d] = packbf2(a0, a1);
    float b0 = r.w00 * bflo(r.g00b[d]) + r.w01 * bflo(r.g01b[d]) +
               r.w10 * bflo(r.g10b[d]) + r.w11 * bflo(r.g11b[d]);
    float b1 = r.w00 * bfhi(r.g00b[d]) + r.w01 * bfhi(r.g01b[d]) +
               r.w10 * bfhi(r.g10b[d]) + r.w11 * bfhi(r.g11b[d]);
    o1[d] = packbf2(b0, b1);
  }
}

__global__ __launch_bounds__(512) void k_gemm(const unsigned short* __restrict__ AW,
                                              const unsigned short* __restrict__ XH,
                                              const float* __restrict__ PY,
                                              const float* __restrict__ PX,
                                              const float* __restrict__ MS,
                                              float* __restrict__ out) {
  // double buffer: per buffer 48 KB = A tile [256][64 bf16] (32 KB) + B tile [128][64 bf16] (16 KB)
  __shared__ u32x4 lds2[2][3072];
  unsigned char* ldsbase = (unsigned char*)lds2;

  const int tid = threadIdx.x;
  const int bid = blockIdx.x;
  const int b = bid & 7;          // XCD swizzle: one batch per XCD
  const int s0 = (bid >> 3) * 128;

  const int l = tid & 63;
  const int w = tid >> 6;
  const int wm = (w >> 1) * 64;  // 4 M-waves
  const int wn = (w & 1) * 64;   // 2 N-waves

  const int am = tid & 255;
  const int ah = tid >> 8;
  const unsigned short* arow = AW + am * KTOT + ah * 32;
  const unsigned swa = (unsigned)(am & 7) << 4;

  const int bn = tid >> 2;
  const int bc = (tid & 3) * 16;
  const int s = s0 + bn;
  const unsigned swb = (unsigned)(bn & 7) << 4;
  const unsigned short* xb = XH + b * (64 * 64 * 256);

  f32x4 acc[4][4];
#pragma unroll
  for (int i = 0; i < 4; ++i)
#pragma unroll
    for (int j = 0; j < 4; ++j) acc[i][j] = (f32x4){0.f, 0.f, 0.f, 0.f};

  u32x4 ar[4];
  u32x4 o0, o1;
  Bld bld;

  // prologue: tile 0 -> regs -> buffer 0 (no barrier needed: LDS not yet read)
#pragma unroll
  for (int j = 0; j < 4; ++j) ar[j] = *(const u32x4*)(arow + j * 8);
  loadB(xb, PY, PX, MS, b, 0, 0, bc, s, bld);
  blendB(bld, o0, o1);
  {
    unsigned char* ldsA = ldsbase;
    unsigned char* ldsB = ldsbase + 32768;
    const unsigned abase = (unsigned)am * 128u;
#pragma unroll
    for (int j = 0; j < 4; ++j)
      *(u32x4*)(ldsA + abase + (((unsigned)(ah * 64 + j * 16)) ^ swa)) = ar[j];
    const unsigned bbase = (unsigned)bn * 128u;
    *(u32x4*)(ldsB + bbase + (((unsigned)(bc * 2)) ^ swb)) = o0;
    *(u32x4*)(ldsB + bbase + (((unsigned)(bc * 2 + 16)) ^ swb)) = o1;
  }

  for (int ks = 0; ks < 36; ++ks) {
    const int cur = ks & 1;
    unsigned char* ldsA = ldsbase + cur * 49152;
    unsigned char* ldsB = ldsA + 32768;
    unsigned char* ldsAn = ldsbase + (cur ^ 1) * 49152;
    unsigned char* ldsBn = ldsAn + 32768;

    // issue next tile's global loads before the barrier (latency hides under MFMA)
    if (ks + 1 < 36) {
      int kn = (ks + 1) >> 2, cn = ((ks + 1) & 3) << 6;
#pragma unroll
      for (int j = 0; j < 4; ++j)
        ar[j] = *(const u32x4*)(arow + kn * 256 + cn + j * 8);
      loadB(xb, PY, PX, MS, b, kn, cn, bc, s, bld);
    }

    __syncthreads();  // buf[cur] writes visible; buf[cur^1] reads (iter ks-1) done

#pragma unroll
    for (int kk = 0; kk < 2; ++kk) {
      bf16x8 af[4], bfr[4];
      const unsigned co = (unsigned)(kk * 64 + ((l >> 4) * 16));
#pragma unroll
      for (int i = 0; i < 4; ++i) {
        int row = wm + i * 16 + (l & 15);
        af[i] = *(const bf16x8*)(ldsA + (unsigned)row * 128u +
                                 (co ^ ((unsigned)(row & 7) << 4)));
      }
#pragma unroll
      for (int j = 0; j < 4; ++j) {
        int col = wn + j * 16 + (l & 15);
        bfr[j] = *(const bf16x8*)(ldsB + (unsigned)col * 128u +
                                  (co ^ ((unsigned)(col & 7) << 4)));
      }
#pragma unroll
      for (int i = 0; i < 4; ++i)
#pragma unroll
        for (int j = 0; j < 4; ++j)
          acc[i][j] = __builtin_amdgcn_mfma_f32_16x16x32_bf16(af[i], bfr[j],
                                                              acc[i][j], 0, 0, 0);
    }

    // blend + write NEXT tile into the other buffer (read side untouched)
    if (ks + 1 < 36) {
      blendB(bld, o0, o1);
      const unsigned abase = (unsigned)am * 128u;
#pragma unroll
      for (int j = 0; j < 4; ++j)
        *(u32x4*)(ldsAn + abase + (((unsigned)(ah * 64 + j * 16)) ^ swa)) = ar[j];
      const unsigned bbase = (unsigned)bn * 128u;
      *(u32x4*)(ldsBn + bbase + (((unsigned)(bc * 2)) ^ swb)) = o0;
      *(u32x4*)(ldsBn + bbase + (((unsigned)(bc * 2 + 16)) ^ swb)) = o1;
    }
  }

  // epilogue: D layout col=lane&15, row=(lane>>4)*4+reg (m89)
  const int cn2 = l & 15;
  const int r0 = (l >> 4) * 4;
#pragma unroll
  for (int i = 0; i < 4; ++i) {
#pragma unroll
    for (int j = 0; j < 4; ++j) {
      int sc = s0 + wn + j * 16 + cn2;
#pragma unroll
      for (int r = 0; r < 4; ++r) {
        int o = wm + i * 16 + r0 + r;
        out[((b * 256 + o) << 12) + sc] = acc[i][j][r];
      }
    }
  }
}

extern "C" void kernel_launch(void* const* d_in, const int* in_sizes, int n_in,
                              void* d_out, int out_size, void* d_ws, size_t ws_size,
                              hipStream_t stream) {
  const float* x = (const float*)d_in[0];
  const float* wof = (const float*)d_in[1];
  const float* wc = (const float*)d_in[2];
  float* out = (float*)d_out;
  char* ws = (char*)d_ws;

  // ws layout (total 20.8 MB)
  unsigned short* XH = (unsigned short*)(ws);              // 16,777,216 B
  unsigned short* AW = (unsigned short*)(ws + 16777216);   //  1,179,648 B
  unsigned short* AOH = (unsigned short*)(ws + 17956864);  //    147,456 B
  unsigned short* AOL = (unsigned short*)(ws + 18104320);  //    147,456 B
  float* PY = (float*)(ws + 18251776);                     //  1,179,648 B
  float* PX = (float*)(ws + 19431424);                     //  1,179,648 B
  float* MS = (float*)(ws + 20611072);                     //  1,179,648 B (end 21,790,720)

  // XL (bf16 residual of x, NHWC, 16 MB) lives in d_out: only read by
  // k_offc_mfma, which completes before k_gemm overwrites d_out.
  unsigned short* XL = (unsigned short*)d_out;

  k_nhwc<<<512, 256, 0, stream>>>(x, XH, XL);
  k_wprep<<<2304, 256, 0, stream>>>(wc, AW);
  k_wprep_off<<<288, 256, 0, stream>>>(wof, AOH, AOL);
  k_offc_mfma<<<512, 256, 0, stream>>>(AOH, AOL, XH, XL, PY, PX, MS);
  k_xform2<<<1152, 256, 0, stream>>>(PY, PX, MS);
  k_gemm<<<256, 512, 0, stream>>>(AW, XH, PY, PX, MS, out);
}